// Round 13
// baseline (529.019 us; speedup 1.0000x reference)
//
#include <hip/hip_runtime.h>

typedef float f32x4 __attribute__((ext_vector_type(4)));

#define TSTEPS 500
#define BDIM 64
#define CIN 512
#define COUT 512
#define MTOT (TSTEPS * BDIM)   // 32000
#define NCH (BDIM * CIN)       // 32768
#define SNEUR (BDIM * COUT)    // 32768
#define OUTN ((size_t)TSTEPS * SNEUR + SNEUR)

#define AL64 0.95122942450071400909   // math.exp(-0.001/0.02), f64
#define BL64 (1.0 - AL64)

__global__ __launch_bounds__(256) void fill_const_f32(
    float* __restrict__ p, size_t n, float c) {
  size_t i = (size_t)blockIdx.x * 256 + threadIdx.x;
  const size_t stride = (size_t)gridDim.x * 256;
  for (; i < n; i += stride) p[i] = c;
}

// ---------------------------------------------------------------------------
// f32 trace scan (np-exact): tr = fl(fl(a*tr) + x)
// ---------------------------------------------------------------------------
__global__ __launch_bounds__(256) void trace32(
    const float* __restrict__ X, float* __restrict__ TR,
    const float* __restrict__ alpha) {
  const int j = blockIdx.x * 256 + threadIdx.x;  // b*512 + ci
  const float a = fminf(fmaxf(alpha[0], 0.0f), 0.9999f);
  float tr = 0.0f;
#pragma unroll 10
  for (int t = 0; t < TSTEPS; ++t) {
    float x = X[(size_t)t * NCH + j];
    tr = __fadd_rn(__fmul_rn(a, tr), x);  // explicit _rn: no contraction
    TR[(size_t)t * NCH + j] = tr;
  }
}

// ---------------------------------------------------------------------------
// Fused CUR = (X@W) + (TR@W), np/BLAS-faithful reduction order per element:
//   each of the four chains (xw/tr x head k<384 / tail k>=384) is a single
//   ascending-k f32 FMA chain; combine = fadd(fadd(xH,xT), fadd(tH,tT)).
// 64x64 tile, BK=16, 256 threads, 4x4 outputs/thread, padded LDS.
// ---------------------------------------------------------------------------
__global__ __launch_bounds__(256) void gemm_fused(
    const float* __restrict__ X, const float* __restrict__ TR,
    const float* __restrict__ W, float* __restrict__ CUR) {
  __shared__ __align__(16) float Ax[64][20];
  __shared__ __align__(16) float At[64][20];
  __shared__ __align__(16) float Bs[16][68];
  const int tid = threadIdx.x;
  const int bm = blockIdx.y * 64, bn = blockIdx.x * 64;
  const int ar = tid >> 2, ak = (tid & 3) * 4;   // A loader: 64 x 16
  const int bk = tid >> 4, bn4 = (tid & 15) * 4; // B loader: 16 x 64
  const int ty = tid >> 4, tx = tid & 15;        // 4x4 out at (ty*4, tx*4)

  float xH[4][4] = {{0.0f}}, xT[4][4] = {{0.0f}};
  float tH[4][4] = {{0.0f}}, tT[4][4] = {{0.0f}};

#define GSTEP(ACCX, ACCT)                                                   \
  {                                                                         \
    *(f32x4*)&Ax[ar][ak] =                                                  \
        *(const f32x4*)&X[(size_t)(bm + ar) * CIN + kt * 16 + ak];          \
    *(f32x4*)&At[ar][ak] =                                                  \
        *(const f32x4*)&TR[(size_t)(bm + ar) * CIN + kt * 16 + ak];         \
    *(f32x4*)&Bs[bk][bn4] =                                                 \
        *(const f32x4*)&W[(size_t)(kt * 16 + bk) * COUT + bn + bn4];        \
    __syncthreads();                                                        \
    _Pragma("unroll") for (int kg = 0; kg < 4; ++kg) {                      \
      f32x4 ax[4], at[4];                                                   \
      _Pragma("unroll") for (int i = 0; i < 4; ++i) {                       \
        ax[i] = *(const f32x4*)&Ax[ty * 4 + i][kg * 4];                     \
        at[i] = *(const f32x4*)&At[ty * 4 + i][kg * 4];                     \
      }                                                                     \
      _Pragma("unroll") for (int k2 = 0; k2 < 4; ++k2) {                    \
        f32x4 b4 = *(const f32x4*)&Bs[kg * 4 + k2][tx * 4];                 \
        _Pragma("unroll") for (int i = 0; i < 4; ++i)                       \
          _Pragma("unroll") for (int jj = 0; jj < 4; ++jj) {                \
            ACCX[i][jj] = fmaf(ax[i][k2], b4[jj], ACCX[i][jj]);             \
            ACCT[i][jj] = fmaf(at[i][k2], b4[jj], ACCT[i][jj]);             \
          }                                                                 \
      }                                                                     \
    }                                                                       \
    __syncthreads();                                                        \
  }

  for (int kt = 0; kt < 24; ++kt) GSTEP(xH, tH);   // head: k in [0,384)
  for (int kt = 24; kt < 32; ++kt) GSTEP(xT, tT);  // tail: k in [384,512)
#undef GSTEP

#pragma unroll
  for (int i = 0; i < 4; ++i) {
    f32x4 v;
#pragma unroll
    for (int jj = 0; jj < 4; ++jj)
      v[jj] = __fadd_rn(__fadd_rn(xH[i][jj], xT[i][jj]),
                        __fadd_rn(tH[i][jj], tT[i][jj]));
    *(f32x4*)&CUR[(size_t)(bm + ty * 4 + i) * COUT + bn + tx * 4] = v;
  }
}

// ---------------------------------------------------------------------------
// f32 LIF chain (np-exact): v = fl(fl(AL*v) + fl(BL*cur)); s = (v-1 > 0);
// hard reset. spikes {0,1}; rates = count/500 (np mean of exact-int f32 sum).
// ---------------------------------------------------------------------------
__global__ __launch_bounds__(256) void lif32(
    const float* __restrict__ CUR, float* __restrict__ spikes,
    float* __restrict__ rates) {
  const int j = blockIdx.x * 256 + threadIdx.x;  // b*512 + n
  const float AL = (float)AL64, BL = (float)BL64;
  float v = 0.0f;
  int cnt = 0;
#pragma unroll 10
  for (int t = 0; t < TSTEPS; ++t) {
    float cur = CUR[(size_t)t * SNEUR + j];
    v = __fadd_rn(__fmul_rn(AL, v), __fmul_rn(BL, cur));
    int sp = __fadd_rn(v, -1.0f) > 0.0f;
    cnt += sp;
    spikes[(size_t)t * SNEUR + j] = sp ? 1.0f : 0.0f;
    v = sp ? 0.0f : v;
  }
  rates[j] = __fdiv_rn((float)cnt, 500.0f);
}

extern "C" void kernel_launch(void* const* d_in, const int* in_sizes, int n_in,
                              void* d_out, int out_size, void* d_ws, size_t ws_size,
                              hipStream_t stream) {
  float* out = (float*)d_out;  // f32: spikes [500*64*512] ++ rates [64*512]

  float flag = 0.0f;
  const float* X = nullptr;
  const float* W = nullptr;
  const float* AP = nullptr;
  if (n_in != 3) {
    flag = 11.0f;
  } else {
    for (int i = 0; i < 3; ++i) {
      if (in_sizes[i] == 16384000) X = (const float*)d_in[i];
      else if (in_sizes[i] == 262144) W = (const float*)d_in[i];
      else if (in_sizes[i] == 1) AP = (const float*)d_in[i];
    }
    if (!X || !W || !AP) flag = 13.0f;
    else if (out_size != (int)OUTN) flag = 17.0f;
    else if (ws_size < 2ull * MTOT * CIN * 4ull) flag = 23.0f;
  }
  if (flag != 0.0f) {
    fill_const_f32<<<dim3(2048), dim3(256), 0, stream>>>(out, OUTN, flag);
    return;
  }

  float* TR = (float*)d_ws;                     // trace [32000,512] f32
  float* CUR = TR + (size_t)MTOT * CIN;         // current [32000,512] f32

  trace32<<<dim3(NCH / 256), dim3(256), 0, stream>>>(X, TR, AP);
  dim3 gg(COUT / 64, MTOT / 64);  // (8, 500)
  gemm_fused<<<gg, dim3(256), 0, stream>>>(X, TR, W, CUR);
  lif32<<<dim3(SNEUR / 256), dim3(256), 0, stream>>>(
      CUR, out, out + (size_t)TSTEPS * SNEUR);
}